// Round 1
// baseline (17595.688 us; speedup 1.0000x reference)
//
#include <hip/hip_runtime.h>
#include <cstdint>
#include <cstddef>

#define HID 1024
#define INP 512
#define BATCH 128
#define TSTEPS 256
#define R4 (4*HID)      // 4096 fused gate rows, gate-interleaved r = j*4+g
#define KD (INP+HID)    // 1536

using short8 = __attribute__((ext_vector_type(8))) short;
using f32x4  = __attribute__((ext_vector_type(4))) float;

static __device__ __forceinline__ unsigned short f2bf(float f) {
    union { float f; unsigned int u; } v; v.f = f;
    unsigned int r = v.u + 0x7fffu + ((v.u >> 16) & 1u);   // RNE
    return (unsigned short)(r >> 16);
}
static __device__ __forceinline__ float bf2f(unsigned short b) {
    union { unsigned int u; float f; } v; v.u = ((unsigned int)b) << 16;
    return v.f;
}
static __device__ __forceinline__ float sigmoid_f(float z) {
    return 1.0f / (1.0f + __expf(-z));
}
static __device__ __forceinline__ float tanh_f(float z) {
    return 2.0f / (1.0f + __expf(-2.0f * z)) - 1.0f;
}

// ---------------------------------------------------------------------------
// Prep 1: fused, gate-interleaved weight matrix, split into bf16 hi + lo.
// Wcat[r][k], r = j*4 + gate (gate: 0=g,1=i,2=f,3=o), k<512 -> W?x, else W?h.
// ---------------------------------------------------------------------------
__global__ void prep_w(const float* __restrict__ Wgx, const float* __restrict__ Wix,
                       const float* __restrict__ Wfx, const float* __restrict__ Wox,
                       const float* __restrict__ Wgh, const float* __restrict__ Wih,
                       const float* __restrict__ Wfh, const float* __restrict__ Woh,
                       unsigned short* __restrict__ whi, unsigned short* __restrict__ wlo)
{
    const int r = blockIdx.x;          // 0..4095
    const int j = r >> 2;
    const int g = r & 3;
    const float* wx = (g == 0 ? Wgx : g == 1 ? Wix : g == 2 ? Wfx : Wox) + (size_t)j * INP;
    const float* wh = (g == 0 ? Wgh : g == 1 ? Wih : g == 2 ? Wfh : Woh) + (size_t)j * HID;
    const size_t base = (size_t)r * KD;
    for (int col = threadIdx.x; col < KD; col += 256) {
        float f = (col < INP) ? wx[col] : wh[col - INP];
        unsigned short hi = f2bf(f);
        unsigned short lo = f2bf(f - bf2f(hi));
        whi[base + col] = hi;
        wlo[base + col] = lo;
    }
}

// ---------------------------------------------------------------------------
// Prep 2: x (B,T,I) fp32 -> xp (T,B,I) bf16 hi/lo (B-operand layout [b][k]).
// ---------------------------------------------------------------------------
__global__ void prep_x(const float* __restrict__ x,
                       unsigned short* __restrict__ xhi, unsigned short* __restrict__ xlo)
{
    const size_t e = ((size_t)blockIdx.x * 256 + threadIdx.x) * 4;   // 4 floats / thread
    const int i = (int)(e & 511);
    const int b = (int)((e >> 9) & 127);
    const int t = (int)(e >> 16);
    const float4 v = *(const float4*)(x + (((size_t)b * TSTEPS + t) << 9) + i);
    ushort4 hi, lo;
    hi.x = f2bf(v.x); lo.x = f2bf(v.x - bf2f(hi.x));
    hi.y = f2bf(v.y); lo.y = f2bf(v.y - bf2f(hi.y));
    hi.z = f2bf(v.z); lo.z = f2bf(v.z - bf2f(hi.z));
    hi.w = f2bf(v.w); lo.w = f2bf(v.w - bf2f(hi.w));
    const size_t o = (((size_t)t * BATCH + b) << 9) + i;
    *(ushort4*)(xhi + o) = hi;
    *(ushort4*)(xlo + o) = lo;
}

// ---------------------------------------------------------------------------
// Prep 3: c state copy (H,B); h0 (H,B) -> bf16 hi/lo in [b][j] layout.
// ---------------------------------------------------------------------------
__global__ void prep_state(const float* __restrict__ cin, const float* __restrict__ hin,
                           float* __restrict__ cdst,
                           unsigned short* __restrict__ h0h, unsigned short* __restrict__ h0l)
{
    const int idx = blockIdx.x * 256 + threadIdx.x;   // 0..131071
    cdst[idx] = cin[idx];
    const int jj = idx >> 7;
    const int b  = idx & 127;
    float f = hin[idx];
    unsigned short hh = f2bf(f);
    h0h[(size_t)b * HID + jj] = hh;
    h0l[(size_t)b * HID + jj] = f2bf(f - bf2f(hh));
}

// ---------------------------------------------------------------------------
// One LSTM timestep. Grid 128 blocks x 256 threads (4 waves).
// Block (bx): rows R0=(bx>>1)*64 (16 j's x 4 gates), cols C0=(bx&1)*64.
// Wave wv: 16 rows (R0 + wv*16) x 64 cols, 4 MFMA col-tiles, K=1536.
// Split-bf16: acc += Ah*Bh + Ah*Bl + Al*Bh  (error ~1e-5 rel).
// ---------------------------------------------------------------------------
__global__ __launch_bounds__(256, 1) void lstm_step(
    const unsigned short* __restrict__ whi, const unsigned short* __restrict__ wlo,
    const unsigned short* __restrict__ xhi, const unsigned short* __restrict__ xlo,
    const unsigned short* __restrict__ hinh, const unsigned short* __restrict__ hinl,
    unsigned short* __restrict__ houth, unsigned short* __restrict__ houtl,
    float* __restrict__ cst,
    const float* __restrict__ bg, const float* __restrict__ bi,
    const float* __restrict__ bf_, const float* __restrict__ bo,
    float* __restrict__ outf, int t)
{
    const int tid  = threadIdx.x;
    const int wv   = tid >> 6;
    const int lane = tid & 63;
    const int l15  = lane & 15;
    const int q    = lane >> 4;               // quad 0..3
    const int bx   = blockIdx.x;
    const int R0w  = ((bx >> 1) << 6) + (wv << 4);  // wave 16-row base
    const int C0   = (bx & 1) << 6;
    const int j0   = (bx >> 1) << 4;          // block j base (16 j per block)

    // A operand (weights): A[m=l15][k = q*8 + 0..7], row-major Wcat.
    const unsigned short* pah = whi + (size_t)(R0w + l15) * KD + q * 8;
    const unsigned short* pal = wlo + (size_t)(R0w + l15) * KD + q * 8;
    // B operand (act = [x_t ; h]): B[k][n=l15], stored [b][k], 16B contiguous in k.
    const size_t brow = (size_t)(C0 + l15);
    const unsigned short* pxh = xhi + ((size_t)t * BATCH + brow) * INP + q * 8;
    const unsigned short* pxl = xlo + ((size_t)t * BATCH + brow) * INP + q * 8;
    const unsigned short* phh = hinh + brow * HID + q * 8;
    const unsigned short* phl = hinl + brow * HID + q * 8;

    f32x4 acc0 = {0.f,0.f,0.f,0.f};
    f32x4 acc1 = {0.f,0.f,0.f,0.f};
    f32x4 acc2 = {0.f,0.f,0.f,0.f};
    f32x4 acc3 = {0.f,0.f,0.f,0.f};

#define LD8(p) (*(const short8*)(p))
#define MFMA(a,b,c) __builtin_amdgcn_mfma_f32_16x16x32_bf16((a),(b),(c),0,0,0)
#define TRIPLE(acc, Ah, Al, Bh, Bl)      \
    acc = MFMA(Ah, Bh, acc);             \
    acc = MFMA(Ah, Bl, acc);             \
    acc = MFMA(Al, Bh, acc);

    // ---- x part: K = 0..511, 16 chunks of 32 ----
#pragma unroll 2
    for (int kc = 0; kc < INP / 32; ++kc) {
        const int ko = kc * 32;
        short8 Ah = LD8(pah + ko);
        short8 Al = LD8(pal + ko);
        short8 B0h = LD8(pxh + ko);
        short8 B1h = LD8(pxh + 16 * INP + ko);
        short8 B2h = LD8(pxh + 32 * INP + ko);
        short8 B3h = LD8(pxh + 48 * INP + ko);
        short8 B0l = LD8(pxl + ko);
        short8 B1l = LD8(pxl + 16 * INP + ko);
        short8 B2l = LD8(pxl + 32 * INP + ko);
        short8 B3l = LD8(pxl + 48 * INP + ko);
        TRIPLE(acc0, Ah, Al, B0h, B0l)
        TRIPLE(acc1, Ah, Al, B1h, B1l)
        TRIPLE(acc2, Ah, Al, B2h, B2l)
        TRIPLE(acc3, Ah, Al, B3h, B3l)
    }
    // ---- h part: K = 512..1535, 32 chunks of 32 ----
#pragma unroll 2
    for (int kc = 0; kc < HID / 32; ++kc) {
        const int ko = kc * 32;
        short8 Ah = LD8(pah + INP + ko);
        short8 Al = LD8(pal + INP + ko);
        short8 B0h = LD8(phh + ko);
        short8 B1h = LD8(phh + 16 * HID + ko);
        short8 B2h = LD8(phh + 32 * HID + ko);
        short8 B3h = LD8(phh + 48 * HID + ko);
        short8 B0l = LD8(phl + ko);
        short8 B1l = LD8(phl + 16 * HID + ko);
        short8 B2l = LD8(phl + 32 * HID + ko);
        short8 B3l = LD8(phl + 48 * HID + ko);
        TRIPLE(acc0, Ah, Al, B0h, B0l)
        TRIPLE(acc1, Ah, Al, B1h, B1l)
        TRIPLE(acc2, Ah, Al, B2h, B2l)
        TRIPLE(acc3, Ah, Al, B3h, B3l)
    }

    // ---- epilogue: lane holds gates g,i,f,o (regs 0..3) for one j, 4 cols ----
    // D layout (m89-verified): col = lane&15, row = q*4 + reg; rows are j*4+gate.
    const int j  = j0 + (wv << 2) + q;
    const int jl = (wv << 2) + q;            // 0..15 within block
    const float bgv = bg[j], biv = bi[j], bfv = bf_[j], bov = bo[j];

    __shared__ unsigned short hti[16][64];
    __shared__ unsigned short htl[16][64];

#define EPI(acc, nt)                                                    \
    {                                                                   \
        const int b = C0 + (nt)*16 + l15;                               \
        float gg = tanh_f(acc[0] + bgv);                                \
        float ig = sigmoid_f(acc[1] + biv);                             \
        float fg = sigmoid_f(acc[2] + bfv);                             \
        float og = sigmoid_f(acc[3] + bov);                             \
        const size_t ci = (size_t)j * BATCH + b;                        \
        float cn = gg * ig + cst[ci] * fg;                              \
        cst[ci] = cn;                                                   \
        float hh = tanh_f(cn) * og;                                     \
        unsigned short hb = f2bf(hh);                                   \
        hti[jl][(nt)*16 + l15] = hb;                                    \
        htl[jl][(nt)*16 + l15] = f2bf(hh - bf2f(hb));                   \
        if (outf) outf[ci] = hh;                                        \
    }

    EPI(acc0, 0)
    EPI(acc1, 1)
    EPI(acc2, 2)
    EPI(acc3, 3)

    __syncthreads();

    // transpose-write h to [b][j] layout, 8B per thread, coalesced-ish
    {
        const int b    = tid >> 2;            // 0..63
        const int jseg = (tid & 3) << 2;      // 0,4,8,12
        ushort4 vh, vl;
        vh.x = hti[jseg + 0][b]; vh.y = hti[jseg + 1][b];
        vh.z = hti[jseg + 2][b]; vh.w = hti[jseg + 3][b];
        vl.x = htl[jseg + 0][b]; vl.y = htl[jseg + 1][b];
        vl.z = htl[jseg + 2][b]; vl.w = htl[jseg + 3][b];
        *(ushort4*)(houth + (size_t)(C0 + b) * HID + j0 + jseg) = vh;
        *(ushort4*)(houtl + (size_t)(C0 + b) * HID + j0 + jseg) = vl;
    }
#undef EPI
#undef TRIPLE
#undef MFMA
#undef LD8
}

// ---------------------------------------------------------------------------
extern "C" void kernel_launch(void* const* d_in, const int* in_sizes, int n_in,
                              void* d_out, int out_size, void* d_ws, size_t ws_size,
                              hipStream_t stream)
{
    const float* x   = (const float*)d_in[0];
    const float* c0  = (const float*)d_in[1];
    const float* h0  = (const float*)d_in[2];
    const float* Wgx = (const float*)d_in[3];
    const float* Wix = (const float*)d_in[4];
    const float* Wfx = (const float*)d_in[5];
    const float* Wox = (const float*)d_in[6];
    const float* Wgh = (const float*)d_in[7];
    const float* Wih = (const float*)d_in[8];
    const float* Wfh = (const float*)d_in[9];
    const float* Woh = (const float*)d_in[10];
    const float* bg  = (const float*)d_in[11];
    const float* bi  = (const float*)d_in[12];
    const float* bf  = (const float*)d_in[13];
    const float* bo  = (const float*)d_in[14];

    // ws layout (elements are ushort unless noted); total ~89.5 MiB
    unsigned short* whi = (unsigned short*)d_ws;
    unsigned short* wlo = whi + (size_t)R4 * KD;                 // +6291456
    unsigned short* xhi = wlo + (size_t)R4 * KD;
    unsigned short* xlo = xhi + (size_t)TSTEPS * BATCH * INP;    // +16777216
    unsigned short* hb0h = xlo + (size_t)TSTEPS * BATCH * INP;
    unsigned short* hb1h = hb0h + (size_t)BATCH * HID;
    unsigned short* hb0l = hb1h + (size_t)BATCH * HID;
    unsigned short* hb1l = hb0l + (size_t)BATCH * HID;
    float* cst = (float*)(hb1l + (size_t)BATCH * HID);

    unsigned short* hbh[2] = { hb0h, hb1h };
    unsigned short* hbl[2] = { hb0l, hb1l };

    prep_w<<<dim3(R4), dim3(256), 0, stream>>>(Wgx, Wix, Wfx, Wox, Wgh, Wih, Wfh, Woh, whi, wlo);
    prep_x<<<dim3(16384), dim3(256), 0, stream>>>(x, xhi, xlo);
    prep_state<<<dim3(512), dim3(256), 0, stream>>>(c0, h0, cst, hbh[0], hbl[0]);

    float* outp = (float*)d_out;
    for (int t = 0; t < TSTEPS; ++t) {
        lstm_step<<<dim3(128), dim3(256), 0, stream>>>(
            whi, wlo, xhi, xlo,
            hbh[t & 1], hbl[t & 1], hbh[(t + 1) & 1], hbl[(t + 1) & 1],
            cst, bg, bi, bf, bo,
            (t == TSTEPS - 1) ? outp : nullptr, t);
    }
}

// Round 2
// 10052.007 us; speedup vs baseline: 1.7505x; 1.7505x over previous
//
#include <hip/hip_runtime.h>
#include <cstdint>
#include <cstddef>

#define HID 1024
#define INP 512
#define BATCH 128
#define TSTEPS 256
#define R4 (4*HID)      // 4096 fused gate rows, gate-interleaved r = j*4+g
#define KD (INP+HID)    // 1536

using short8 = __attribute__((ext_vector_type(8))) short;
using f32x4  = __attribute__((ext_vector_type(4))) float;

static __device__ __forceinline__ unsigned short f2bf(float f) {
    union { float f; unsigned int u; } v; v.f = f;
    unsigned int r = v.u + 0x7fffu + ((v.u >> 16) & 1u);   // RNE
    return (unsigned short)(r >> 16);
}
static __device__ __forceinline__ float bf2f(unsigned short b) {
    union { unsigned int u; float f; } v; v.u = ((unsigned int)b) << 16;
    return v.f;
}
static __device__ __forceinline__ float sigmoid_f(float z) {
    return 1.0f / (1.0f + __expf(-z));
}
static __device__ __forceinline__ float tanh_f(float z) {
    return 2.0f / (1.0f + __expf(-2.0f * z)) - 1.0f;
}

// ---------------------------------------------------------------------------
// Prep 1: fused, gate-interleaved weight matrix, split into bf16 hi + lo.
// Wcat[r][k], r = j*4 + gate (gate: 0=g,1=i,2=f,3=o), k<512 -> W?x, else W?h.
// ---------------------------------------------------------------------------
__global__ void prep_w(const float* __restrict__ Wgx, const float* __restrict__ Wix,
                       const float* __restrict__ Wfx, const float* __restrict__ Wox,
                       const float* __restrict__ Wgh, const float* __restrict__ Wih,
                       const float* __restrict__ Wfh, const float* __restrict__ Woh,
                       unsigned short* __restrict__ whi, unsigned short* __restrict__ wlo)
{
    const int r = blockIdx.x;          // 0..4095
    const int j = r >> 2;
    const int g = r & 3;
    const float* wx = (g == 0 ? Wgx : g == 1 ? Wix : g == 2 ? Wfx : Wox) + (size_t)j * INP;
    const float* wh = (g == 0 ? Wgh : g == 1 ? Wih : g == 2 ? Wfh : Woh) + (size_t)j * HID;
    const size_t base = (size_t)r * KD;
    for (int col = threadIdx.x; col < KD; col += 256) {
        float f = (col < INP) ? wx[col] : wh[col - INP];
        unsigned short hi = f2bf(f);
        unsigned short lo = f2bf(f - bf2f(hi));
        whi[base + col] = hi;
        wlo[base + col] = lo;
    }
}

// ---------------------------------------------------------------------------
// Prep 2: x (B,T,I) fp32 -> xp (T,B,I) bf16 hi/lo (B-operand layout [b][k]).
// ---------------------------------------------------------------------------
__global__ void prep_x(const float* __restrict__ x,
                       unsigned short* __restrict__ xhi, unsigned short* __restrict__ xlo)
{
    const size_t e = ((size_t)blockIdx.x * 256 + threadIdx.x) * 4;   // 4 floats / thread
    const int i = (int)(e & 511);
    const int b = (int)((e >> 9) & 127);
    const int t = (int)(e >> 16);
    const float4 v = *(const float4*)(x + (((size_t)b * TSTEPS + t) << 9) + i);
    ushort4 hi, lo;
    hi.x = f2bf(v.x); lo.x = f2bf(v.x - bf2f(hi.x));
    hi.y = f2bf(v.y); lo.y = f2bf(v.y - bf2f(hi.y));
    hi.z = f2bf(v.z); lo.z = f2bf(v.z - bf2f(hi.z));
    hi.w = f2bf(v.w); lo.w = f2bf(v.w - bf2f(hi.w));
    const size_t o = (((size_t)t * BATCH + b) << 9) + i;
    *(ushort4*)(xhi + o) = hi;
    *(ushort4*)(xlo + o) = lo;
}

// ---------------------------------------------------------------------------
// Prep 3: c state copy (H,B); h0 (H,B) -> bf16 hi/lo in [b][j] layout.
// ---------------------------------------------------------------------------
__global__ void prep_state(const float* __restrict__ cin, const float* __restrict__ hin,
                           float* __restrict__ cdst,
                           unsigned short* __restrict__ h0h, unsigned short* __restrict__ h0l)
{
    const int idx = blockIdx.x * 256 + threadIdx.x;   // 0..131071
    cdst[idx] = cin[idx];
    const int jj = idx >> 7;
    const int b  = idx & 127;
    float f = hin[idx];
    unsigned short hh = f2bf(f);
    h0h[(size_t)b * HID + jj] = hh;
    h0l[(size_t)b * HID + jj] = f2bf(f - bf2f(hh));
}

// ---------------------------------------------------------------------------
// One LSTM timestep. Grid 256 blocks x 256 threads (4 waves), 1 block/CU.
// XCD swizzle: xcd = bx&7 owns rowslices xcd*16..+15 (32 gate-rows each) so
// each XCD's L2 keeps its 3.15 MB weight slice resident across launches.
// Block: rowslice (32 gate-rows = 8 j's) x 64 batch cols (colbase 0/64).
// Wave wv: rows R0w = rowslice*32 + (wv&1)*16, cols C0w = colbase+(wv>>1)*32,
// 2 MFMA col-tiles of 16. K = 1536. Split-bf16 triple product.
// ---------------------------------------------------------------------------
__global__ __launch_bounds__(256, 1) void lstm_step(
    const unsigned short* __restrict__ whi, const unsigned short* __restrict__ wlo,
    const unsigned short* __restrict__ xhi, const unsigned short* __restrict__ xlo,
    const unsigned short* __restrict__ hinh, const unsigned short* __restrict__ hinl,
    unsigned short* __restrict__ houth, unsigned short* __restrict__ houtl,
    float* __restrict__ cst,
    const float* __restrict__ bg, const float* __restrict__ bi,
    const float* __restrict__ bf_, const float* __restrict__ bo,
    float* __restrict__ outf, int t)
{
    const int tid  = threadIdx.x;
    const int wv   = tid >> 6;
    const int lane = tid & 63;
    const int l15  = lane & 15;
    const int q    = lane >> 4;               // quad 0..3
    const int bx   = blockIdx.x;

    const int xcd      = bx & 7;
    const int i        = bx >> 3;                 // 0..31 within XCD
    const int rowslice = xcd * 16 + (i >> 1);     // 0..127 (32 gate-rows each)
    const int colbase  = (i & 1) << 6;            // 0 or 64

    const int R0w = rowslice * 32 + (wv & 1) * 16;   // wave 16-row base
    const int C0w = colbase + (wv >> 1) * 32;        // wave 32-col base
    const int j0b = rowslice * 8;                    // block j base (8 j's)

    // A operand (weights): A[m=l15][k = q*8 + 0..7], row-major Wcat.
    const unsigned short* pah = whi + (size_t)(R0w + l15) * KD + q * 8;
    const unsigned short* pal = wlo + (size_t)(R0w + l15) * KD + q * 8;
    // B operand (act = [x_t ; h]): B[k][n=l15], stored [b][k], 16B contiguous in k.
    const size_t brow = (size_t)(C0w + l15);
    const unsigned short* pxh = xhi + ((size_t)t * BATCH + brow) * INP + q * 8;
    const unsigned short* pxl = xlo + ((size_t)t * BATCH + brow) * INP + q * 8;
    const unsigned short* phh = hinh + brow * HID + q * 8;
    const unsigned short* phl = hinl + brow * HID + q * 8;

    f32x4 acc0 = {0.f,0.f,0.f,0.f};
    f32x4 acc1 = {0.f,0.f,0.f,0.f};

#define LD8(p) (*(const short8*)(p))
#define MFMA(a,b,c) __builtin_amdgcn_mfma_f32_16x16x32_bf16((a),(b),(c),0,0,0)
#define TRIPLE(acc, Ah, Al, Bh, Bl)      \
    acc = MFMA(Ah, Bh, acc);             \
    acc = MFMA(Ah, Bl, acc);             \
    acc = MFMA(Al, Bh, acc);

    // ---- x part: K = 0..511, 16 chunks of 32 ----
#pragma unroll 4
    for (int kc = 0; kc < INP / 32; ++kc) {
        const int ko = kc * 32;
        short8 Ah  = LD8(pah + ko);
        short8 Al  = LD8(pal + ko);
        short8 B0h = LD8(pxh + ko);
        short8 B1h = LD8(pxh + 16 * INP + ko);
        short8 B0l = LD8(pxl + ko);
        short8 B1l = LD8(pxl + 16 * INP + ko);
        TRIPLE(acc0, Ah, Al, B0h, B0l)
        TRIPLE(acc1, Ah, Al, B1h, B1l)
    }
    // ---- h part: K = 512..1535, 32 chunks of 32 ----
#pragma unroll 4
    for (int kc = 0; kc < HID / 32; ++kc) {
        const int ko = kc * 32;
        short8 Ah  = LD8(pah + INP + ko);
        short8 Al  = LD8(pal + INP + ko);
        short8 B0h = LD8(phh + ko);
        short8 B1h = LD8(phh + 16 * HID + ko);
        short8 B0l = LD8(phl + ko);
        short8 B1l = LD8(phl + 16 * HID + ko);
        TRIPLE(acc0, Ah, Al, B0h, B0l)
        TRIPLE(acc1, Ah, Al, B1h, B1l)
    }

    // ---- epilogue: lane holds gates g,i,f,o (regs 0..3) for one j, 2 cols ----
    // D layout (m89-verified): col = lane&15, row = q*4 + reg; rows are j*4+gate.
    const int j  = (R0w >> 2) + q;               // global j for this lane
    const int jl = j - j0b;                      // 0..7 within block
    const float bgv = bg[j], biv = bi[j], bfv = bf_[j], bov = bo[j];

    __shared__ unsigned short hti[8][64];
    __shared__ unsigned short htl[8][64];

#define EPI(acc, nt)                                                    \
    {                                                                   \
        const int b  = C0w + (nt)*16 + l15;      /* global batch col */ \
        const int cl = (b - colbase);            /* 0..63 in block  */  \
        float gg = tanh_f(acc[0] + bgv);                                \
        float ig = sigmoid_f(acc[1] + biv);                             \
        float fg = sigmoid_f(acc[2] + bfv);                             \
        float og = sigmoid_f(acc[3] + bov);                             \
        const size_t ci = (size_t)j * BATCH + b;                        \
        float cn = gg * ig + cst[ci] * fg;                              \
        cst[ci] = cn;                                                   \
        float hh = tanh_f(cn) * og;                                     \
        unsigned short hb = f2bf(hh);                                   \
        hti[jl][cl] = hb;                                               \
        htl[jl][cl] = f2bf(hh - bf2f(hb));                              \
        if (outf) outf[ci] = hh;                                        \
    }

    EPI(acc0, 0)
    EPI(acc1, 1)

    __syncthreads();

    // transpose-write h to [b][j] layout: threads 0..127, 16B per thread.
    if (tid < 128) {
        const int bl   = tid >> 1;            // 0..63
        const int half = tid & 1;             // 0 = hi, 1 = lo
        unsigned short (*src)[64] = half ? htl : hti;
        ushort4 v0, v1;
        v0.x = src[0][bl]; v0.y = src[1][bl]; v0.z = src[2][bl]; v0.w = src[3][bl];
        v1.x = src[4][bl]; v1.y = src[5][bl]; v1.z = src[6][bl]; v1.w = src[7][bl];
        unsigned short* dst = (half ? houtl : houth) +
                              (size_t)(colbase + bl) * HID + j0b;
        *(ushort4*)(dst)     = v0;
        *(ushort4*)(dst + 4) = v1;
    }
#undef EPI
#undef TRIPLE
#undef MFMA
#undef LD8
}

// ---------------------------------------------------------------------------
extern "C" void kernel_launch(void* const* d_in, const int* in_sizes, int n_in,
                              void* d_out, int out_size, void* d_ws, size_t ws_size,
                              hipStream_t stream)
{
    const float* x   = (const float*)d_in[0];
    const float* c0  = (const float*)d_in[1];
    const float* h0  = (const float*)d_in[2];
    const float* Wgx = (const float*)d_in[3];
    const float* Wix = (const float*)d_in[4];
    const float* Wfx = (const float*)d_in[5];
    const float* Wox = (const float*)d_in[6];
    const float* Wgh = (const float*)d_in[7];
    const float* Wih = (const float*)d_in[8];
    const float* Wfh = (const float*)d_in[9];
    const float* Woh = (const float*)d_in[10];
    const float* bg  = (const float*)d_in[11];
    const float* bi  = (const float*)d_in[12];
    const float* bf  = (const float*)d_in[13];
    const float* bo  = (const float*)d_in[14];

    // ws layout (elements are ushort unless noted); total ~89.5 MiB
    unsigned short* whi = (unsigned short*)d_ws;
    unsigned short* wlo = whi + (size_t)R4 * KD;                 // +6291456
    unsigned short* xhi = wlo + (size_t)R4 * KD;
    unsigned short* xlo = xhi + (size_t)TSTEPS * BATCH * INP;    // +16777216
    unsigned short* hb0h = xlo + (size_t)TSTEPS * BATCH * INP;
    unsigned short* hb1h = hb0h + (size_t)BATCH * HID;
    unsigned short* hb0l = hb1h + (size_t)BATCH * HID;
    unsigned short* hb1l = hb0l + (size_t)BATCH * HID;
    float* cst = (float*)(hb1l + (size_t)BATCH * HID);

    unsigned short* hbh[2] = { hb0h, hb1h };
    unsigned short* hbl[2] = { hb0l, hb1l };

    prep_w<<<dim3(R4), dim3(256), 0, stream>>>(Wgx, Wix, Wfx, Wox, Wgh, Wih, Wfh, Woh, whi, wlo);
    prep_x<<<dim3(16384), dim3(256), 0, stream>>>(x, xhi, xlo);
    prep_state<<<dim3(512), dim3(256), 0, stream>>>(c0, h0, cst, hbh[0], hbl[0]);

    float* outp = (float*)d_out;
    for (int t = 0; t < TSTEPS; ++t) {
        lstm_step<<<dim3(256), dim3(256), 0, stream>>>(
            whi, wlo, xhi, xlo,
            hbh[t & 1], hbl[t & 1], hbh[(t + 1) & 1], hbl[(t + 1) & 1],
            cst, bg, bi, bf, bo,
            (t == TSTEPS - 1) ? outp : nullptr, t);
    }
}

// Round 3
// 6942.787 us; speedup vs baseline: 2.5344x; 1.4478x over previous
//
#include <hip/hip_runtime.h>
#include <cstdint>
#include <cstddef>

#define HID 1024
#define INP 512
#define BATCH 128
#define TSTEPS 256
#define R4 (4*HID)      // 4096 fused gate rows, gate-interleaved r = j*4+g
#define KD (INP+HID)    // 1536

using short8  = __attribute__((ext_vector_type(8))) short;
using f32x16  = __attribute__((ext_vector_type(16))) float;

static __device__ __forceinline__ unsigned short f2bf(float f) {
    union { float f; unsigned int u; } v; v.f = f;
    unsigned int r = v.u + 0x7fffu + ((v.u >> 16) & 1u);   // RNE
    return (unsigned short)(r >> 16);
}
static __device__ __forceinline__ float bf2f(unsigned short b) {
    union { unsigned int u; float f; } v; v.u = ((unsigned int)b) << 16;
    return v.f;
}
static __device__ __forceinline__ float sigmoid_f(float z) {
    return 1.0f / (1.0f + __expf(-z));
}
static __device__ __forceinline__ float tanh_f(float z) {
    return 2.0f / (1.0f + __expf(-2.0f * z)) - 1.0f;
}

// ---------------------------------------------------------------------------
// Prep 1: fused, gate-interleaved weight matrix, split into bf16 hi + lo.
// Wcat[r][k], r = j*4 + gate (0=g,1=i,2=f,3=o), k<512 -> W?x, else W?h.
// ---------------------------------------------------------------------------
__global__ void prep_w(const float* __restrict__ Wgx, const float* __restrict__ Wix,
                       const float* __restrict__ Wfx, const float* __restrict__ Wox,
                       const float* __restrict__ Wgh, const float* __restrict__ Wih,
                       const float* __restrict__ Wfh, const float* __restrict__ Woh,
                       unsigned short* __restrict__ whi, unsigned short* __restrict__ wlo)
{
    const int r = blockIdx.x;          // 0..4095
    const int j = r >> 2;
    const int g = r & 3;
    const float* wx = (g == 0 ? Wgx : g == 1 ? Wix : g == 2 ? Wfx : Wox) + (size_t)j * INP;
    const float* wh = (g == 0 ? Wgh : g == 1 ? Wih : g == 2 ? Wfh : Woh) + (size_t)j * HID;
    const size_t base = (size_t)r * KD;
    for (int col = threadIdx.x; col < KD; col += 256) {
        float f = (col < INP) ? wx[col] : wh[col - INP];
        unsigned short hi = f2bf(f);
        unsigned short lo = f2bf(f - bf2f(hi));
        whi[base + col] = hi;
        wlo[base + col] = lo;
    }
}

// ---------------------------------------------------------------------------
// Prep 2: x (B,T,I) fp32 -> xp (T,B,I) bf16 hi/lo (B-operand layout [b][k]).
// ---------------------------------------------------------------------------
__global__ void prep_x(const float* __restrict__ x,
                       unsigned short* __restrict__ xhi, unsigned short* __restrict__ xlo)
{
    const size_t e = ((size_t)blockIdx.x * 256 + threadIdx.x) * 4;   // 4 floats / thread
    const int i = (int)(e & 511);
    const int b = (int)((e >> 9) & 127);
    const int t = (int)(e >> 16);
    const float4 v = *(const float4*)(x + (((size_t)b * TSTEPS + t) << 9) + i);
    ushort4 hi, lo;
    hi.x = f2bf(v.x); lo.x = f2bf(v.x - bf2f(hi.x));
    hi.y = f2bf(v.y); lo.y = f2bf(v.y - bf2f(hi.y));
    hi.z = f2bf(v.z); lo.z = f2bf(v.z - bf2f(hi.z));
    hi.w = f2bf(v.w); lo.w = f2bf(v.w - bf2f(hi.w));
    const size_t o = (((size_t)t * BATCH + b) << 9) + i;
    *(ushort4*)(xhi + o) = hi;
    *(ushort4*)(xlo + o) = lo;
}

// ---------------------------------------------------------------------------
// Prep 3: c state copy (H,B); h0 (H,B) -> bf16 hi/lo in [b][j] layout.
// ---------------------------------------------------------------------------
__global__ void prep_state(const float* __restrict__ cin, const float* __restrict__ hin,
                           float* __restrict__ cdst,
                           unsigned short* __restrict__ h0h, unsigned short* __restrict__ h0l)
{
    const int idx = blockIdx.x * 256 + threadIdx.x;   // 0..131071
    cdst[idx] = cin[idx];
    const int jj = idx >> 7;
    const int b  = idx & 127;
    float f = hin[idx];
    unsigned short hh = f2bf(f);
    h0h[(size_t)b * HID + jj] = hh;
    h0l[(size_t)b * HID + jj] = f2bf(f - bf2f(hh));
}

// ---------------------------------------------------------------------------
// One LSTM timestep. Grid 256 blocks x 512 threads (8 waves), 1 block/CU.
// XCD swizzle: xcd = bx&7 owns rowslices xcd*16..+15 -> per-XCD L2 keeps its
// 3.15 MB weight slice resident across launches.
// Block: 32 gate-rows (8 j's) x 64 batch cols. MFMA 32x32x16_bf16.
// Waves: cw = wv&1 (32-col group), kq = wv>>1 (k-quarter, 384 of K=1536).
// 3 independent accumulator chains (AhBh, AhBl, AlBh); K-partials combined
// in LDS; kq==0 waves run the gate epilogue.
// ---------------------------------------------------------------------------
__global__ __launch_bounds__(512, 2) void lstm_step(
    const unsigned short* __restrict__ whi, const unsigned short* __restrict__ wlo,
    const unsigned short* __restrict__ xhi, const unsigned short* __restrict__ xlo,
    const unsigned short* __restrict__ hinh, const unsigned short* __restrict__ hinl,
    unsigned short* __restrict__ houth, unsigned short* __restrict__ houtl,
    float* __restrict__ cst,
    const float* __restrict__ bg, const float* __restrict__ bi,
    const float* __restrict__ bf_, const float* __restrict__ bo,
    float* __restrict__ outf, int t)
{
    const int tid  = threadIdx.x;
    const int wv   = tid >> 6;
    const int lane = tid & 63;
    const int l31  = lane & 31;
    const int hl   = lane >> 5;               // 0/1: k-subgroup of 8
    const int cw   = wv & 1;                  // 32-col group
    const int kq   = wv >> 1;                 // k-quarter 0..3
    const int bx   = blockIdx.x;

    const int xcd      = bx & 7;
    const int ii       = bx >> 3;
    const int rowslice = xcd * 16 + (ii >> 1);    // 0..127
    const int colbase  = (ii & 1) << 6;           // 0 or 64

    const int R0  = rowslice * 32;            // block gate-row base
    const int J0  = rowslice * 8;             // block j base (8 j's)
    const int col = colbase + cw * 32 + l31;  // this lane's batch column

    // A fragment (32x32x16): A[m=l31][k = hl*8 + e], row-major Wcat.
    const unsigned short* pAh = whi + (size_t)(R0 + l31) * KD + hl * 8;
    const unsigned short* pAl = wlo + (size_t)(R0 + l31) * KD + hl * 8;
    // B fragment: B[k][n=l31], act stored [b][k].
    const unsigned short* pXh = xhi + ((size_t)t * BATCH + col) * INP + hl * 8;
    const unsigned short* pXl = xlo + ((size_t)t * BATCH + col) * INP + hl * 8;
    const unsigned short* pHh = hinh + (size_t)col * HID + hl * 8;
    const unsigned short* pHl = hinl + (size_t)col * HID + hl * 8;

    f32x16 aHH, aHL, aLH;
#pragma unroll
    for (int r = 0; r < 16; ++r) { aHH[r] = 0.f; aHL[r] = 0.f; aLH[r] = 0.f; }

#define LD8(p) (*(const short8*)(p))
#define MFMA32(a,b,c) __builtin_amdgcn_mfma_f32_32x32x16_bf16((a),(b),(c),0,0,0)

    // wave covers k16 indices [kq*24, kq*24+24) of 96 total (x: 0..31, h: 32..95)
    const int kstart16 = kq * 24;
    const int nx = (kq == 0) ? 24 : (kq == 1) ? 8 : 0;

#pragma unroll 4
    for (int kk = 0; kk < nx; ++kk) {
        const int xk = (kstart16 + kk) * 16;
        short8 Ah = LD8(pAh + xk);
        short8 Al = LD8(pAl + xk);
        short8 Bh = LD8(pXh + xk);
        short8 Bl = LD8(pXl + xk);
        aHH = MFMA32(Ah, Bh, aHH);
        aHL = MFMA32(Ah, Bl, aHL);
        aLH = MFMA32(Al, Bh, aLH);
    }
#pragma unroll 4
    for (int kk = nx; kk < 24; ++kk) {
        const int hk = (kstart16 + kk - 32) * 16;    // 0..1008
        short8 Ah = LD8(pAh + INP + hk);
        short8 Al = LD8(pAl + INP + hk);
        short8 Bh = LD8(pHh + hk);
        short8 Bl = LD8(pHl + hk);
        aHH = MFMA32(Ah, Bh, aHH);
        aHL = MFMA32(Ah, Bl, aHL);
        aLH = MFMA32(Al, Bh, aLH);
    }

    f32x16 zs;
#pragma unroll
    for (int r = 0; r < 16; ++r) zs[r] = aHH[r] + aHL[r] + aLH[r];

    // C/D layout (m74/m101): col = lane&31, localrow = (reg&3) + 8*(reg>>2) + 4*hl
    __shared__ float part[3][2][32][32];          // 24 KB k-partials
    __shared__ unsigned short hti[8][64];
    __shared__ unsigned short htl[8][64];

    if (kq != 0) {
#pragma unroll
        for (int r = 0; r < 16; ++r) {
            const int lr = (r & 3) + 8 * (r >> 2) + 4 * hl;
            part[kq - 1][cw][lr][l31] = zs[r];
        }
    }
    __syncthreads();

    if (kq == 0) {
#pragma unroll
        for (int jj = 0; jj < 4; ++jj) {          // reg-quad = one j's 4 gates
            float zg[4];
#pragma unroll
            for (int g = 0; g < 4; ++g) {
                const int r  = 4 * jj + g;
                const int lr = 8 * jj + 4 * hl + g;
                zg[g] = zs[r] + part[0][cw][lr][l31]
                              + part[1][cw][lr][l31]
                              + part[2][cw][lr][l31];
            }
            const int j = J0 + 2 * jj + hl;
            float gg = tanh_f(zg[0] + bg[j]);
            float ig = sigmoid_f(zg[1] + bi[j]);
            float fg = sigmoid_f(zg[2] + bf_[j]);
            float og = sigmoid_f(zg[3] + bo[j]);
            const size_t ci = (size_t)j * BATCH + col;
            float cn = gg * ig + cst[ci] * fg;
            cst[ci] = cn;
            float hh = tanh_f(cn) * og;
            unsigned short hb = f2bf(hh);
            const int jl = 2 * jj + hl;           // 0..7
            const int cl = cw * 32 + l31;         // 0..63
            hti[jl][cl] = hb;
            htl[jl][cl] = f2bf(hh - bf2f(hb));
            if (outf) outf[ci] = hh;
        }
    }
    __syncthreads();

    // transpose-write h to [b][j] layout: threads 0..127, 16B per thread.
    if (tid < 128) {
        const int bl   = tid >> 1;            // 0..63
        const int half = tid & 1;             // 0 = hi, 1 = lo
        unsigned short (*src)[64] = half ? htl : hti;
        ushort4 v0, v1;
        v0.x = src[0][bl]; v0.y = src[1][bl]; v0.z = src[2][bl]; v0.w = src[3][bl];
        v1.x = src[4][bl]; v1.y = src[5][bl]; v1.z = src[6][bl]; v1.w = src[7][bl];
        unsigned short* dst = (half ? houtl : houth) +
                              (size_t)(colbase + bl) * HID + J0;
        *(ushort4*)(dst)     = v0;
        *(ushort4*)(dst + 4) = v1;
    }
#undef MFMA32
#undef LD8
}

// ---------------------------------------------------------------------------
extern "C" void kernel_launch(void* const* d_in, const int* in_sizes, int n_in,
                              void* d_out, int out_size, void* d_ws, size_t ws_size,
                              hipStream_t stream)
{
    const float* x   = (const float*)d_in[0];
    const float* c0  = (const float*)d_in[1];
    const float* h0  = (const float*)d_in[2];
    const float* Wgx = (const float*)d_in[3];
    const float* Wix = (const float*)d_in[4];
    const float* Wfx = (const float*)d_in[5];
    const float* Wox = (const float*)d_in[6];
    const float* Wgh = (const float*)d_in[7];
    const float* Wih = (const float*)d_in[8];
    const float* Wfh = (const float*)d_in[9];
    const float* Woh = (const float*)d_in[10];
    const float* bg  = (const float*)d_in[11];
    const float* bi  = (const float*)d_in[12];
    const float* bf  = (const float*)d_in[13];
    const float* bo  = (const float*)d_in[14];

    // ws layout (elements are ushort unless noted); total ~89.5 MiB
    unsigned short* whi = (unsigned short*)d_ws;
    unsigned short* wlo = whi + (size_t)R4 * KD;
    unsigned short* xhi = wlo + (size_t)R4 * KD;
    unsigned short* xlo = xhi + (size_t)TSTEPS * BATCH * INP;
    unsigned short* hb0h = xlo + (size_t)TSTEPS * BATCH * INP;
    unsigned short* hb1h = hb0h + (size_t)BATCH * HID;
    unsigned short* hb0l = hb1h + (size_t)BATCH * HID;
    unsigned short* hb1l = hb0l + (size_t)BATCH * HID;
    float* cst = (float*)(hb1l + (size_t)BATCH * HID);

    unsigned short* hbh[2] = { hb0h, hb1h };
    unsigned short* hbl[2] = { hb0l, hb1l };

    prep_w<<<dim3(R4), dim3(256), 0, stream>>>(Wgx, Wix, Wfx, Wox, Wgh, Wih, Wfh, Woh, whi, wlo);
    prep_x<<<dim3(16384), dim3(256), 0, stream>>>(x, xhi, xlo);
    prep_state<<<dim3(512), dim3(256), 0, stream>>>(c0, h0, cst, hbh[0], hbl[0]);

    float* outp = (float*)d_out;
    for (int t = 0; t < TSTEPS; ++t) {
        lstm_step<<<dim3(256), dim3(512), 0, stream>>>(
            whi, wlo, xhi, xlo,
            hbh[t & 1], hbl[t & 1], hbh[(t + 1) & 1], hbl[(t + 1) & 1],
            cst, bg, bi, bf, bo,
            (t == TSTEPS - 1) ? outp : nullptr, t);
    }
}

// Round 4
// 3699.825 us; speedup vs baseline: 4.7558x; 1.8765x over previous
//
#include <hip/hip_runtime.h>
#include <cstdint>
#include <cstddef>

#define HID 1024
#define INP 512
#define BATCH 128
#define TSTEPS 256
#define R4 (4*HID)      // 4096 fused gate rows, gate-interleaved r = j*4+g
#define KD (INP+HID)    // 1536
#define NK16 96         // K / 16
#define NK16X 32        // x part
#define NK16H 64        // h part

using short8  = __attribute__((ext_vector_type(8))) short;
using f32x16  = __attribute__((ext_vector_type(16))) float;

static __device__ __forceinline__ unsigned short f2bf(float f) {
    union { float f; unsigned int u; } v; v.f = f;
    unsigned int r = v.u + 0x7fffu + ((v.u >> 16) & 1u);   // RNE
    return (unsigned short)(r >> 16);
}
static __device__ __forceinline__ float bf2f(unsigned short b) {
    union { unsigned int u; float f; } v; v.u = ((unsigned int)b) << 16;
    return v.f;
}
static __device__ __forceinline__ float sigmoid_f(float z) {
    return 1.0f / (1.0f + __expf(-z));
}
static __device__ __forceinline__ float tanh_f(float z) {
    return 2.0f / (1.0f + __expf(-2.0f * z)) - 1.0f;
}

// ---------------------------------------------------------------------------
// Fragment layouts (32x32x16 MFMA, content identical to round-3 verified map):
//   A: lane l holds W[rowslice*32 + (l&31)][k16*16 + (l>>5)*8 + e], e=0..7
//      wfrag[s:128][k16:96][p:2][lane:64][e:8]   (p: 0=hi, 1=lo)
//   B: lane l holds act[col = cg*32 + (l&31)][k16*16 + (l>>5)*8 + e]
//      xfrag[t:256][k16:32][cg:4][p:2][lane:64][e:8]
//      hfrag[k16:64][cg:4][p:2][lane:64][e:8]
// Every K-loop global load is base + lane*16B -> contiguous 1 KB per wave.
// ---------------------------------------------------------------------------

// Prep 1: weights -> wfrag. Grid (96, 128) = (k16, s), 256 threads.
__global__ void prep_w(const float* __restrict__ Wgx, const float* __restrict__ Wix,
                       const float* __restrict__ Wfx, const float* __restrict__ Wox,
                       const float* __restrict__ Wgh, const float* __restrict__ Wih,
                       const float* __restrict__ Wfh, const float* __restrict__ Woh,
                       unsigned short* __restrict__ wfrag)
{
    const int k16 = blockIdx.x;        // 0..95
    const int s   = blockIdx.y;        // 0..127
    const int tid  = threadIdx.x;
    const int lane = tid >> 2;         // 0..63
    const int e0   = (tid & 3) * 2;    // 0,2,4,6
    const int row  = s * 32 + (lane & 31);
    const int k    = k16 * 16 + (lane >> 5) * 8 + e0;
    const int j = row >> 2;
    const int g = row & 3;
    float f0, f1;
    if (k < INP) {
        const float* wx = (g == 0 ? Wgx : g == 1 ? Wix : g == 2 ? Wfx : Wox) + (size_t)j * INP;
        f0 = wx[k]; f1 = wx[k + 1];
    } else {
        const float* wh = (g == 0 ? Wgh : g == 1 ? Wih : g == 2 ? Wfh : Woh) + (size_t)j * HID;
        f0 = wh[k - INP]; f1 = wh[k - INP + 1];
    }
    ushort2 hi, lo;
    hi.x = f2bf(f0); lo.x = f2bf(f0 - bf2f(hi.x));
    hi.y = f2bf(f1); lo.y = f2bf(f1 - bf2f(hi.y));
    unsigned short* base = wfrag + ((size_t)(s * NK16 + k16) * 2) * 512 + lane * 8 + e0;
    *(ushort2*)(base)       = hi;
    *(ushort2*)(base + 512) = lo;
}

// Prep 2: x -> xfrag. Grid (32, 256) = (k16x, t), 256 threads.
__global__ void prep_x(const float* __restrict__ x, unsigned short* __restrict__ xfrag)
{
    const int k16x = blockIdx.x;       // 0..31
    const int t    = blockIdx.y;       // 0..255
    const int tid  = threadIdx.x;
    const int cg   = tid >> 6;         // 0..3
    const int lane = tid & 63;
    const int col  = cg * 32 + (lane & 31);
    const int k0   = k16x * 16 + (lane >> 5) * 8;
    const float* src = x + ((size_t)col * TSTEPS + t) * INP + k0;
    const float4 v0 = *(const float4*)(src);
    const float4 v1 = *(const float4*)(src + 4);
    ushort4 h0, l0, h1, l1;
    h0.x = f2bf(v0.x); l0.x = f2bf(v0.x - bf2f(h0.x));
    h0.y = f2bf(v0.y); l0.y = f2bf(v0.y - bf2f(h0.y));
    h0.z = f2bf(v0.z); l0.z = f2bf(v0.z - bf2f(h0.z));
    h0.w = f2bf(v0.w); l0.w = f2bf(v0.w - bf2f(h0.w));
    h1.x = f2bf(v1.x); l1.x = f2bf(v1.x - bf2f(h1.x));
    h1.y = f2bf(v1.y); l1.y = f2bf(v1.y - bf2f(h1.y));
    h1.z = f2bf(v1.z); l1.z = f2bf(v1.z - bf2f(h1.z));
    h1.w = f2bf(v1.w); l1.w = f2bf(v1.w - bf2f(h1.w));
    unsigned short* base = xfrag +
        ((size_t)(((size_t)t * NK16X + k16x) * 4 + cg) * 2) * 512 + lane * 8;
    *(ushort4*)(base)           = h0;
    *(ushort4*)(base + 4)       = h1;
    *(ushort4*)(base + 512)     = l0;
    *(ushort4*)(base + 512 + 4) = l1;
}

// Prep 3: c copy; h0 (H,B) -> hfrag[0]. 512 blocks x 256.
__global__ void prep_state(const float* __restrict__ cin, const float* __restrict__ hin,
                           float* __restrict__ cdst, unsigned short* __restrict__ hfrag0)
{
    const int idx = blockIdx.x * 256 + threadIdx.x;   // 0..131071
    cdst[idx] = cin[idx];
    const int j = idx >> 7;
    const int b = idx & 127;
    float f = hin[idx];
    unsigned short hh = f2bf(f);
    unsigned short hl = f2bf(f - bf2f(hh));
    const int k16h = j >> 4;
    const int hlf  = (j >> 3) & 1;
    const int e    = j & 7;
    const int cg   = b >> 5;
    const int lane = 32 * hlf + (b & 31);
    unsigned short* base = hfrag0 +
        ((size_t)((k16h * 4 + cg) * 2) * 512) + lane * 8 + e;
    base[0]   = hh;
    base[512] = hl;
}

// ---------------------------------------------------------------------------
// One LSTM timestep. Grid 256 x 512 (8 waves), 1 block/CU.
// XCD swizzle: xcd = bx&7 owns rowslices xcd*16..+15 (per-XCD L2-resident
// 3.15 MB weight slice). Block: 32 gate-rows (8 j) x 64 cols.
// Waves: cw = wv&1 (32-col group), kq = wv>>1 (k-quarter of 24 k16).
// All K-loop loads are contiguous 1 KB wave-loads from fragment-major bufs.
// ---------------------------------------------------------------------------
__global__ __launch_bounds__(512, 2) void lstm_step(
    const unsigned short* __restrict__ wfrag,
    const unsigned short* __restrict__ xfrag,
    const unsigned short* __restrict__ hin,
    unsigned short* __restrict__ hout,
    float* __restrict__ cst,
    const float* __restrict__ bg, const float* __restrict__ bi,
    const float* __restrict__ bf_, const float* __restrict__ bo,
    float* __restrict__ outf, int t)
{
    const int tid  = threadIdx.x;
    const int wv   = tid >> 6;
    const int lane = tid & 63;
    const int l31  = lane & 31;
    const int hl   = lane >> 5;
    const int cw   = wv & 1;
    const int kq   = wv >> 1;
    const int bx   = blockIdx.x;

    const int xcd     = bx & 7;
    const int ii      = bx >> 3;
    const int s       = xcd * 16 + (ii >> 1);     // rowslice 0..127
    const int colbase = (ii & 1) << 6;
    const int cg      = (colbase >> 5) + cw;      // global col-group 0..3
    const int col     = cg * 32 + l31;
    const int J0      = s * 8;

    const int k0 = kq * 24;
    const int nx = (kq == 0) ? 24 : (kq == 1) ? 8 : 0;

    const unsigned short* pW = wfrag + ((size_t)(s * NK16 + k0) * 2) * 512 + lane * 8;
    const unsigned short* pX = xfrag +
        ((size_t)(((size_t)t * NK16X + k0) * 4 + cg) * 2) * 512 + lane * 8;

    f32x16 aHH, aHL, aLH;
#pragma unroll
    for (int r = 0; r < 16; ++r) { aHH[r] = 0.f; aHL[r] = 0.f; aLH[r] = 0.f; }

#define LD8(p) (*(const short8*)(p))
#define MFMA32(a,b,c) __builtin_amdgcn_mfma_f32_32x32x16_bf16((a),(b),(c),0,0,0)

#pragma unroll 8
    for (int kk = 0; kk < nx; ++kk) {
        short8 Ah = LD8(pW);
        short8 Al = LD8(pW + 512);
        short8 Bh = LD8(pX);
        short8 Bl = LD8(pX + 512);
        pW += 1024; pX += 4096;
        aHH = MFMA32(Ah, Bh, aHH);
        aHL = MFMA32(Ah, Bl, aHL);
        aLH = MFMA32(Al, Bh, aLH);
    }
    const unsigned short* pH = hin +
        ((size_t)((k0 + nx - 32) * 4 + cg) * 2) * 512 + lane * 8;
#pragma unroll 8
    for (int kk = nx; kk < 24; ++kk) {
        short8 Ah = LD8(pW);
        short8 Al = LD8(pW + 512);
        short8 Bh = LD8(pH);
        short8 Bl = LD8(pH + 512);
        pW += 1024; pH += 4096;
        aHH = MFMA32(Ah, Bh, aHH);
        aHL = MFMA32(Ah, Bl, aHL);
        aLH = MFMA32(Al, Bh, aLH);
    }

    f32x16 zs;
#pragma unroll
    for (int r = 0; r < 16; ++r) zs[r] = aHH[r] + aHL[r] + aLH[r];

    // C/D layout (m74/m101): col = lane&31, localrow = (reg&3) + 8*(reg>>2) + 4*hl
    __shared__ float part[3][2][32][32];          // 24 KB k-partials
    __shared__ unsigned short hti[8][64];
    __shared__ unsigned short htl[8][64];

    if (kq != 0) {
#pragma unroll
        for (int r = 0; r < 16; ++r) {
            const int lr = (r & 3) + 8 * (r >> 2) + 4 * hl;
            part[kq - 1][cw][lr][l31] = zs[r];
        }
    }
    __syncthreads();

    if (kq == 0) {
#pragma unroll
        for (int jj = 0; jj < 4; ++jj) {          // reg-quad = one j's 4 gates
            float zg[4];
#pragma unroll
            for (int g = 0; g < 4; ++g) {
                const int r  = 4 * jj + g;
                const int lr = 8 * jj + 4 * hl + g;
                zg[g] = zs[r] + part[0][cw][lr][l31]
                              + part[1][cw][lr][l31]
                              + part[2][cw][lr][l31];
            }
            const int j = J0 + 2 * jj + hl;
            float gg = tanh_f(zg[0] + bg[j]);
            float ig = sigmoid_f(zg[1] + bi[j]);
            float fg = sigmoid_f(zg[2] + bf_[j]);
            float og = sigmoid_f(zg[3] + bo[j]);
            const size_t ci = (size_t)j * BATCH + col;
            float cn = gg * ig + cst[ci] * fg;
            cst[ci] = cn;
            float hh = tanh_f(cn) * og;
            unsigned short hb = f2bf(hh);
            const int jl = 2 * jj + hl;           // 0..7
            const int cl = cw * 32 + l31;         // 0..63 local col
            hti[jl][cl] = hb;
            htl[jl][cl] = f2bf(hh - bf2f(hb));
            if (outf) outf[ci] = hh;
        }
    }
    __syncthreads();

    // h write-back in fragment-major layout: 256 threads, contiguous 8B each.
    if (tid < 256) {
        const int cgl = tid >> 7;             // local col-group 0/1
        const int p   = (tid >> 6) & 1;       // hi/lo
        const int c5  = (tid >> 1) & 31;      // col within group
        const int q4  = (tid & 1) * 4;        // e quad
        const int coll = cgl * 32 + c5;
        unsigned short (*src)[64] = p ? htl : hti;
        ushort4 v;
        v.x = src[q4 + 0][coll]; v.y = src[q4 + 1][coll];
        v.z = src[q4 + 2][coll]; v.w = src[q4 + 3][coll];
        const int k16h = s >> 1;
        const int lh   = 32 * (s & 1) + c5;
        const int cgg  = (colbase >> 5) + cgl;
        unsigned short* dst = hout +
            ((size_t)((k16h * 4 + cgg) * 2 + p) * 512) + lh * 8 + q4;
        *(ushort4*)dst = v;
    }
#undef MFMA32
#undef LD8
}

// ---------------------------------------------------------------------------
extern "C" void kernel_launch(void* const* d_in, const int* in_sizes, int n_in,
                              void* d_out, int out_size, void* d_ws, size_t ws_size,
                              hipStream_t stream)
{
    const float* x   = (const float*)d_in[0];
    const float* c0  = (const float*)d_in[1];
    const float* h0  = (const float*)d_in[2];
    const float* Wgx = (const float*)d_in[3];
    const float* Wix = (const float*)d_in[4];
    const float* Wfx = (const float*)d_in[5];
    const float* Wox = (const float*)d_in[6];
    const float* Wgh = (const float*)d_in[7];
    const float* Wih = (const float*)d_in[8];
    const float* Wfh = (const float*)d_in[9];
    const float* Woh = (const float*)d_in[10];
    const float* bg  = (const float*)d_in[11];
    const float* bi  = (const float*)d_in[12];
    const float* bf  = (const float*)d_in[13];
    const float* bo  = (const float*)d_in[14];

    // ws layout (ushort elements unless noted), total ~93.8 MiB
    unsigned short* wfrag = (unsigned short*)d_ws;                         // 128*96*2*512
    unsigned short* xfrag = wfrag + (size_t)128 * NK16 * 2 * 512;          // 256*32*4*2*512
    unsigned short* hf0   = xfrag + (size_t)TSTEPS * NK16X * 4 * 2 * 512;  // 64*4*2*512
    unsigned short* hf1   = hf0 + (size_t)NK16H * 4 * 2 * 512;
    float* cst            = (float*)(hf1 + (size_t)NK16H * 4 * 2 * 512);

    unsigned short* hf[2] = { hf0, hf1 };

    prep_w<<<dim3(NK16, 128), dim3(256), 0, stream>>>(Wgx, Wix, Wfx, Wox,
                                                      Wgh, Wih, Wfh, Woh, wfrag);
    prep_x<<<dim3(NK16X, TSTEPS), dim3(256), 0, stream>>>(x, xfrag);
    prep_state<<<dim3(512), dim3(256), 0, stream>>>(c0, h0, cst, hf[0]);

    float* outp = (float*)d_out;
    for (int t = 0; t < TSTEPS; ++t) {
        lstm_step<<<dim3(256), dim3(512), 0, stream>>>(
            wfrag, xfrag, hf[t & 1], hf[(t + 1) & 1],
            cst, bg, bi, bf, bo,
            (t == TSTEPS - 1) ? outp : nullptr, t);
    }
}